// Round 1
// baseline (138.780 us; speedup 1.0000x reference)
//
#include <hip/hip_runtime.h>
#include <math.h>

// VQC simulator: 8 qubits -> 256 amplitudes, one block (256 thr) per batch elem.
// Phase 1 (RY cycles + CNOT rings) is REAL-only (RY/CNOT real, |0> real).
// CNOT ring composed into a single permutation gather per cycle.
// Ping-pong LDS buffers -> one __syncthreads per gate.
// Qubit q <-> flat bit (7-q). Measured qubits 3,7 -> bits 16,1.

#define DIM 256
#define NCYC 4
#define NGATES 10

__global__ __launch_bounds__(256) void vqcnn_kernel(
    const float* __restrict__ x,          // (B, 4, 8)
    const float* __restrict__ crx_theta,  // (10,)
    const float* __restrict__ w1,         // (10, 2) row-major
    const float* __restrict__ b1,         // (10,)
    const float* __restrict__ w2,         // (1, 10)
    const float* __restrict__ b2,         // (1,)
    float* __restrict__ out)              // (B, 1)
{
    const int b   = blockIdx.x;
    const int idx = threadIdx.x;

    __shared__ float rb[2][DIM];
    __shared__ float ib[2][DIM];
    __shared__ float cosv[NCYC * 8], sinv[NCYC * 8];
    __shared__ float ccos[NGATES],   csin[NGATES];

    // stage per-batch RY angles (32) and shared CRX angles (10) as cos/sin
    if (idx < 32) {
        float h = 0.5f * x[b * 32 + idx];
        cosv[idx] = cosf(h);
        sinv[idx] = sinf(h);
    } else if (idx < 32 + NGATES) {
        float h = 0.5f * crx_theta[idx - 32];
        ccos[idx - 32] = cosf(h);
        csin[idx - 32] = sinf(h);
    }

    // Composed source index for one CNOT ring: gates CNOT(q, q+1 mod 8),
    // q = 0..7 applied in order. s_after[idx] = s_before[j] with
    // j = sigma_0(sigma_1(...sigma_7(idx)...)).
    int j = idx;
    #pragma unroll
    for (int q = 7; q >= 0; --q) {
        const int cb = 1 << (7 - q);
        const int tb = 1 << (7 - ((q + 1) & 7));
        if (j & cb) j ^= tb;
    }

    rb[0][idx] = (idx == 0) ? 1.0f : 0.0f;
    __syncthreads();

    int cur = 0;

    // ---- Phase 1: 4 cycles of (8 RY + CNOT ring), real arithmetic ----
    for (int cyc = 0; cyc < NCYC; ++cyc) {
        #pragma unroll
        for (int q = 0; q < 8; ++q) {
            const float c   = cosv[cyc * 8 + q];
            const float s   = sinv[cyc * 8 + q];
            const int   bit = 1 << (7 - q);
            const float self = rb[cur][idx];
            const float part = rb[cur][idx ^ bit];
            // bit==0: c*self - s*part ; bit==1: c*self + s*part
            rb[cur ^ 1][idx] = c * self + ((idx & bit) ? s : -s) * part;
            __syncthreads();
            cur ^= 1;
        }
        rb[cur ^ 1][idx] = rb[cur][j];  // composed CNOT ring
        __syncthreads();
        cur ^= 1;
    }

    // ---- Phase 2: 10 CRX gates (state becomes complex here) ----
    ib[cur][idx] = 0.0f;
    __syncthreads();
    #pragma unroll
    for (int i = 0; i < NGATES; ++i) {
        const int   c    = i & 7;
        const int   t    = (i + 1) & 7;
        const int   cbit = 1 << (7 - c);
        const int   tbit = 1 << (7 - t);
        const float co = ccos[i], s = csin[i];
        float zr = rb[cur][idx], zi = ib[cur][idx];
        if (idx & cbit) {
            const float pr = rb[cur][idx ^ tbit];
            const float pi = ib[cur][idx ^ tbit];
            // new = cos*self + (-i*sin)*partner
            const float nr = co * zr + s * pi;
            const float ni = co * zi - s * pr;
            zr = nr; zi = ni;
        }
        rb[cur ^ 1][idx] = zr;
        ib[cur ^ 1][idx] = zi;
        __syncthreads();
        cur ^= 1;
    }

    // ---- Measurement: <Z_3>, <Z_7> then MLP on thread 0 ----
    const float zr = rb[cur][idx], zi = ib[cur][idx];
    const float p  = zr * zr + zi * zi;
    rb[cur ^ 1][idx] = (idx & 16) ? -p : p;  // qubit 3 -> bit 4
    ib[cur ^ 1][idx] = (idx & 1)  ? -p : p;  // qubit 7 -> bit 0
    __syncthreads();
    if (idx < 64) {
        float v3 = rb[cur ^ 1][idx]       + rb[cur ^ 1][idx + 64]
                 + rb[cur ^ 1][idx + 128] + rb[cur ^ 1][idx + 192];
        float v7 = ib[cur ^ 1][idx]       + ib[cur ^ 1][idx + 64]
                 + ib[cur ^ 1][idx + 128] + ib[cur ^ 1][idx + 192];
        #pragma unroll
        for (int o = 32; o > 0; o >>= 1) {
            v3 += __shfl_down(v3, o);
            v7 += __shfl_down(v7, o);
        }
        if (idx == 0) {
            float acc = b2[0];
            #pragma unroll
            for (int u = 0; u < 10; ++u) {
                const float hu = tanhf(w1[2 * u] * v3 + w1[2 * u + 1] * v7 + b1[u]);
                acc += w2[u] * hu;
            }
            out[b] = 1.0f / (1.0f + expf(-acc));
        }
    }
}

extern "C" void kernel_launch(void* const* d_in, const int* in_sizes, int n_in,
                              void* d_out, int out_size, void* d_ws, size_t ws_size,
                              hipStream_t stream) {
    const float* x         = (const float*)d_in[0];
    const float* crx_theta = (const float*)d_in[1];
    const float* w1        = (const float*)d_in[2];
    const float* b1        = (const float*)d_in[3];
    const float* w2        = (const float*)d_in[4];
    const float* b2        = (const float*)d_in[5];
    float* out = (float*)d_out;

    const int B = in_sizes[0] / 32;  // x is (B, 4, 8)
    vqcnn_kernel<<<B, 256, 0, stream>>>(x, crx_theta, w1, b1, w2, b2, out);
}

// Round 2
// 96.828 us; speedup vs baseline: 1.4333x; 1.4333x over previous
//
#include <hip/hip_runtime.h>
#include <math.h>

// One wave (64 lanes) per batch element. 256 amplitudes = 64 lanes x 4 slots,
// amp idx = lane*4 + slot  (amp bits 7..2 = lane bits 5..0, amp bits 1..0 = slot).
// Phase 1 (RY+CNOT rings) is real-only. CNOT ring composed into one GF(2)-linear
// permutation: src_lane = gray(lane) ^ (slot_bit0 ? 48 : 0), src_slot = f(slot, lane0).
// All cross-lane traffic via ds_bpermute with precomputed addresses; zero LDS
// allocation, zero barriers. Angle sincos computed once per wave in lanes 0..41,
// broadcast per gate via v_readlane (VALU pipe, keeps LDS pipe free).

#define RLF(v, i) __int_as_float(__builtin_amdgcn_readlane(__float_as_int(v), (i)))
#define BPF(a, v) __int_as_float(__builtin_amdgcn_ds_bpermute((a), __float_as_int(v)))

__global__ __launch_bounds__(256) void vqcnn_wave(
    const float* __restrict__ x,          // (B, 4, 8)
    const float* __restrict__ crx_theta,  // (10,)
    const float* __restrict__ w1,         // (10, 2)
    const float* __restrict__ b1,         // (10,)
    const float* __restrict__ w2,         // (1, 10)
    const float* __restrict__ b2,         // (1,)
    float* __restrict__ out)              // (B, 1)
{
    const int lane = threadIdx.x & 63;
    const int b    = blockIdx.x * 4 + (threadIdx.x >> 6);

    // ---- per-wave angle table: lanes 0..31 RY, lanes 32..41 CRX ----
    float cv, sv;
    {
        float ang = 0.0f;
        if (lane < 32)      ang = x[b * 32 + lane];
        else if (lane < 42) ang = crx_theta[lane - 32];
        __sincosf(0.5f * ang, &sv, &cv);
    }

    // precomputed bpermute byte addresses (lane^mask)*4
    const int a1  = (lane ^ 1)  << 2;
    const int a2  = (lane ^ 2)  << 2;
    const int a4  = (lane ^ 4)  << 2;
    const int a8  = (lane ^ 8)  << 2;
    const int a16 = (lane ^ 16) << 2;
    const int a32 = (lane ^ 32) << 2;
    const int g4  = (lane ^ (lane >> 1)) << 2;  // gray(lane)*4 : ring src lane
    const int g4b = g4 ^ (48 << 2);             //  ... ^48 for odd slots
    const bool l0 = (lane & 1) != 0;

    float v0 = (lane == 0) ? 1.0f : 0.0f;
    float v1 = 0.0f, v2 = 0.0f, v3 = 0.0f;

#define RY_LANE(ia, mask, am) {                                              \
    const float c = RLF(cv, (ia)), s = RLF(sv, (ia));                        \
    const float ss = (lane & (mask)) ? s : -s;                               \
    const float p0 = BPF((am), v0), p1 = BPF((am), v1);                      \
    const float p2 = BPF((am), v2), p3 = BPF((am), v3);                      \
    v0 = c*v0 + ss*p0; v1 = c*v1 + ss*p1;                                    \
    v2 = c*v2 + ss*p2; v3 = c*v3 + ss*p3; }

#define RY_SLOT1(ia) {                                                       \
    const float c = RLF(cv, (ia)), s = RLF(sv, (ia));                        \
    const float n0 = c*v0 - s*v2, n2 = s*v0 + c*v2;                          \
    const float n1 = c*v1 - s*v3, n3 = s*v1 + c*v3;                          \
    v0 = n0; v1 = n1; v2 = n2; v3 = n3; }

#define RY_SLOT0(ia) {                                                       \
    const float c = RLF(cv, (ia)), s = RLF(sv, (ia));                        \
    const float n0 = c*v0 - s*v1, n1 = s*v0 + c*v1;                          \
    const float n2 = c*v2 - s*v3, n3 = s*v2 + c*v3;                          \
    v0 = n0; v1 = n1; v2 = n2; v3 = n3; }

    // ---- Phase 1: 4 x (8 RY + composed CNOT ring), real arithmetic ----
    #pragma unroll
    for (int cyc = 0; cyc < 4; ++cyc) {
        const int base = cyc * 8;
        RY_LANE(base + 0, 32, a32)   // q=0 -> amp bit7 -> lane bit5
        RY_LANE(base + 1, 16, a16)
        RY_LANE(base + 2,  8, a8)
        RY_LANE(base + 3,  4, a4)
        RY_LANE(base + 4,  2, a2)
        RY_LANE(base + 5,  1, a1)
        RY_SLOT1(base + 6)           // q=6 -> amp bit1
        RY_SLOT0(base + 7)           // q=7 -> amp bit0
        {   // composed CNOT ring: new[idx] = old[j], j = pairwise-xor of adj bits
            const float t0a = BPF(g4,  v0), t0b = BPF(g4,  v2);
            const float t1a = BPF(g4b, v1), t1b = BPF(g4b, v3);
            const float t2a = BPF(g4,  v3), t2b = BPF(g4,  v1);
            const float t3a = BPF(g4b, v2), t3b = BPF(g4b, v0);
            v0 = l0 ? t0b : t0a;
            v1 = l0 ? t1b : t1a;
            v2 = l0 ? t2b : t2a;
            v3 = l0 ? t3b : t3a;
        }
    }

    // ---- Phase 2: 10 CRX gates (complex from here) ----
    float r0 = v0, r1 = v1, r2 = v2, r3 = v3;
    float i0 = 0.f, i1 = 0.f, i2 = 0.f, i3 = 0.f;

#define CRX_LANE(gi, cmask, am) {                                            \
    const float c = RLF(cv, 32 + (gi)), s = RLF(sv, 32 + (gi));              \
    const bool ct = (lane & (cmask)) != 0;                                   \
    const float pr0 = BPF((am), r0), pi0 = BPF((am), i0);                    \
    const float pr1 = BPF((am), r1), pi1 = BPF((am), i1);                    \
    const float pr2 = BPF((am), r2), pi2 = BPF((am), i2);                    \
    const float pr3 = BPF((am), r3), pi3 = BPF((am), i3);                    \
    float nr, ni;                                                            \
    nr = c*r0 + s*pi0; ni = c*i0 - s*pr0; r0 = ct?nr:r0; i0 = ct?ni:i0;      \
    nr = c*r1 + s*pi1; ni = c*i1 - s*pr1; r1 = ct?nr:r1; i1 = ct?ni:i1;      \
    nr = c*r2 + s*pi2; ni = c*i2 - s*pr2; r2 = ct?nr:r2; i2 = ct?ni:i2;      \
    nr = c*r3 + s*pi3; ni = c*i3 - s*pr3; r3 = ct?nr:r3; i3 = ct?ni:i3; }

    CRX_LANE(0, 32, a16)   // c: amp bit7/lane32, t: amp bit6/lane16
    CRX_LANE(1, 16, a8)
    CRX_LANE(2,  8, a4)
    CRX_LANE(3,  4, a2)
    CRX_LANE(4,  2, a1)
    {   // gate 5: ctrl lane bit0, target amp bit1 (slot pairs (0,2),(1,3))
        const float c = RLF(cv, 37), s = RLF(sv, 37);
        const float nr0 = c*r0 + s*i2, ni0 = c*i0 - s*r2;
        const float nr2 = c*r2 + s*i0, ni2 = c*i2 - s*r0;
        const float nr1 = c*r1 + s*i3, ni1 = c*i1 - s*r3;
        const float nr3 = c*r3 + s*i1, ni3 = c*i3 - s*r1;
        r0 = l0?nr0:r0; i0 = l0?ni0:i0; r1 = l0?nr1:r1; i1 = l0?ni1:i1;
        r2 = l0?nr2:r2; i2 = l0?ni2:i2; r3 = l0?nr3:r3; i3 = l0?ni3:i3;
    }
    {   // gate 6: ctrl slot bit1 (slots 2,3), target amp bit0 (pair (2,3))
        const float c = RLF(cv, 38), s = RLF(sv, 38);
        const float nr2 = c*r2 + s*i3, ni2 = c*i2 - s*r3;
        const float nr3 = c*r3 + s*i2, ni3 = c*i3 - s*r2;
        r2 = nr2; i2 = ni2; r3 = nr3; i3 = ni3;
    }
    {   // gate 7: ctrl slot bit0 (slots 1,3), target amp bit7 (lane32)
        const float c = RLF(cv, 39), s = RLF(sv, 39);
        const float pr1 = BPF(a32, r1), pi1 = BPF(a32, i1);
        const float pr3 = BPF(a32, r3), pi3 = BPF(a32, i3);
        const float nr1 = c*r1 + s*pi1, ni1 = c*i1 - s*pr1;
        const float nr3 = c*r3 + s*pi3, ni3 = c*i3 - s*pr3;
        r1 = nr1; i1 = ni1; r3 = nr3; i3 = ni3;
    }
    CRX_LANE(8, 32, a16)
    CRX_LANE(9, 16, a8)

    // ---- probabilities, <Z_3> (amp bit4 -> lane bit2), <Z_7> (amp bit0 -> slot0) ----
    const float p0 = r0*r0 + i0*i0, p1 = r1*r1 + i1*i1;
    const float p2 = r2*r2 + i2*i2, p3 = r3*r3 + i3*i3;
    float vq7 = (p0 + p2) - (p1 + p3);
    float vq3 = (lane & 4) ? -(p0 + p1 + p2 + p3) : (p0 + p1 + p2 + p3);
    vq3 += BPF(a1,  vq3);  vq7 += BPF(a1,  vq7);
    vq3 += BPF(a2,  vq3);  vq7 += BPF(a2,  vq7);
    vq3 += BPF(a4,  vq3);  vq7 += BPF(a4,  vq7);
    vq3 += BPF(a8,  vq3);  vq7 += BPF(a8,  vq7);
    vq3 += BPF(a16, vq3);  vq7 += BPF(a16, vq7);
    vq3 += BPF(a32, vq3);  vq7 += BPF(a32, vq7);

    // ---- MLP (all lanes redundantly; lane 0 stores) ----
    float acc = b2[0];
    #pragma unroll
    for (int u = 0; u < 10; ++u) {
        const float z = w1[2*u] * vq3 + w1[2*u + 1] * vq7 + b1[u];
        const float e = __expf(2.0f * z);
        acc += w2[u] * (1.0f - 2.0f * __builtin_amdgcn_rcpf(e + 1.0f));
    }
    if (lane == 0) out[b] = __builtin_amdgcn_rcpf(1.0f + __expf(-acc));
}

extern "C" void kernel_launch(void* const* d_in, const int* in_sizes, int n_in,
                              void* d_out, int out_size, void* d_ws, size_t ws_size,
                              hipStream_t stream) {
    const float* x         = (const float*)d_in[0];
    const float* crx_theta = (const float*)d_in[1];
    const float* w1        = (const float*)d_in[2];
    const float* b1        = (const float*)d_in[3];
    const float* w2        = (const float*)d_in[4];
    const float* b2        = (const float*)d_in[5];
    float* out = (float*)d_out;

    const int B = in_sizes[0] / 32;  // x is (B, 4, 8)
    vqcnn_wave<<<B / 4, 256, 0, stream>>>(x, crx_theta, w1, b1, w2, b2, out);
}

// Round 3
// 94.700 us; speedup vs baseline: 1.4655x; 1.0225x over previous
//
#include <hip/hip_runtime.h>
#include <math.h>

// One wave per batch element; 256 amps = 64 lanes x 4 slots (amp = lane*4+slot).
// Round-3 change: all power-of-2 lane-XOR exchanges moved off the LDS pipe onto
// the VALU pipe: xor1/2 via DPP quad_perm, xor8 via DPP row_ror:8, xor4 via
// row_half_mirror+quad_perm(xor3), xor16/32 via gfx950 v_permlane{16,32}_swap
// (select-by-equality makes the swap output order irrelevant). Only the
// composed-CNOT-ring gather (irregular gray-code permutation, 8 ops/ring)
// remains on ds_bpermute. Angles broadcast per gate via v_readlane.

#define RLF(v, i) __int_as_float(__builtin_amdgcn_readlane(__float_as_int(v), (i)))
#define BPF(a, v) __int_as_float(__builtin_amdgcn_ds_bpermute((a), __float_as_int(v)))

// VALU-pipe lane permutations (full-rate DPP movs)
#define DPPF(v, ctrl) __uint_as_float((unsigned)__builtin_amdgcn_update_dpp( \
    0, (int)__float_as_uint(v), (ctrl), 0xf, 0xf, true))
#define PX1(v) DPPF((v), 0xB1)               // quad_perm [1,0,3,2] : lane^1
#define PX2(v) DPPF((v), 0x4E)               // quad_perm [2,3,0,1] : lane^2
#define PX4(v) DPPF(DPPF((v), 0x141), 0x1B)  // half_mirror(^7) o quad[3,2,1,0](^3) = ^4
#define PX8(v) DPPF((v), 0x128)              // row_ror:8 == lane^8 within row16

__device__ __forceinline__ float px16(float v, int lane) {
#if __has_builtin(__builtin_amdgcn_permlane16_swap)
    auto r = __builtin_amdgcn_permlane16_swap(__float_as_uint(v), __float_as_uint(v),
                                              false, false);
    const unsigned vb = __float_as_uint(v);
    // one output equals v per-lane, the other is v[lane^16]; pick the other
    return __uint_as_float(r[0] == vb ? r[1] : r[0]);
#else
    return BPF(((lane ^ 16) << 2), v);
#endif
}

__device__ __forceinline__ float px32(float v, int lane) {
#if __has_builtin(__builtin_amdgcn_permlane32_swap)
    auto r = __builtin_amdgcn_permlane32_swap(__float_as_uint(v), __float_as_uint(v),
                                              false, false);
    const unsigned vb = __float_as_uint(v);
    return __uint_as_float(r[0] == vb ? r[1] : r[0]);
#else
    return BPF(((lane ^ 32) << 2), v);
#endif
}

__global__ __launch_bounds__(256) void vqcnn_wave(
    const float* __restrict__ x,          // (B, 4, 8)
    const float* __restrict__ crx_theta,  // (10,)
    const float* __restrict__ w1,         // (10, 2)
    const float* __restrict__ b1,         // (10,)
    const float* __restrict__ w2,         // (1, 10)
    const float* __restrict__ b2,         // (1,)
    float* __restrict__ out)              // (B, 1)
{
    const int lane = threadIdx.x & 63;
    const int b    = blockIdx.x * 4 + (threadIdx.x >> 6);

    // per-wave angle table: lanes 0..31 RY, lanes 32..41 CRX
    float cv, sv;
    {
        float ang = 0.0f;
        if (lane < 32)      ang = x[b * 32 + lane];
        else if (lane < 42) ang = crx_theta[lane - 32];
        __sincosf(0.5f * ang, &sv, &cv);
    }

    // ring-gather bpermute addresses (LDS pipe; only irregular perm left there)
    const int g4  = (lane ^ (lane >> 1)) << 2;  // gray(lane)*4
    const int g4b = g4 ^ (48 << 2);
    const bool l0 = (lane & 1) != 0;

    float v0 = (lane == 0) ? 1.0f : 0.0f;
    float v1 = 0.0f, v2 = 0.0f, v3 = 0.0f;

#define RY_G(ia, mask, PART) {                                               \
    const float c = RLF(cv, (ia)), s = RLF(sv, (ia));                        \
    const float ss = (lane & (mask)) ? s : -s;                               \
    const float p0 = PART(v0), p1 = PART(v1);                                \
    const float p2 = PART(v2), p3 = PART(v3);                                \
    v0 = fmaf(ss, p0, c * v0); v1 = fmaf(ss, p1, c * v1);                    \
    v2 = fmaf(ss, p2, c * v2); v3 = fmaf(ss, p3, c * v3); }

#define PART16(v) px16((v), lane)
#define PART32(v) px32((v), lane)

#define RY_SLOT1(ia) {                                                       \
    const float c = RLF(cv, (ia)), s = RLF(sv, (ia));                        \
    const float n0 = c*v0 - s*v2, n2 = s*v0 + c*v2;                          \
    const float n1 = c*v1 - s*v3, n3 = s*v1 + c*v3;                          \
    v0 = n0; v1 = n1; v2 = n2; v3 = n3; }

#define RY_SLOT0(ia) {                                                       \
    const float c = RLF(cv, (ia)), s = RLF(sv, (ia));                        \
    const float n0 = c*v0 - s*v1, n1 = s*v0 + c*v1;                          \
    const float n2 = c*v2 - s*v3, n3 = s*v2 + c*v3;                          \
    v0 = n0; v1 = n1; v2 = n2; v3 = n3; }

    // ---- Phase 1: 4 x (8 RY + composed CNOT ring), real arithmetic ----
    #pragma unroll
    for (int cyc = 0; cyc < 4; ++cyc) {
        const int base = cyc * 8;
        RY_G(base + 0, 32, PART32)   // q0 -> amp bit7 -> lane^32
        RY_G(base + 1, 16, PART16)
        RY_G(base + 2,  8, PX8)
        RY_G(base + 3,  4, PX4)
        RY_G(base + 4,  2, PX2)
        RY_G(base + 5,  1, PX1)
        RY_SLOT1(base + 6)           // q6 -> amp bit1
        RY_SLOT0(base + 7)           // q7 -> amp bit0
        {   // composed CNOT ring: new[idx] = old[j] (gray-code gather, LDS pipe)
            const float t0a = BPF(g4,  v0), t0b = BPF(g4,  v2);
            const float t1a = BPF(g4b, v1), t1b = BPF(g4b, v3);
            const float t2a = BPF(g4,  v3), t2b = BPF(g4,  v1);
            const float t3a = BPF(g4b, v2), t3b = BPF(g4b, v0);
            v0 = l0 ? t0b : t0a;
            v1 = l0 ? t1b : t1a;
            v2 = l0 ? t2b : t2a;
            v3 = l0 ? t3b : t3a;
        }
    }

    // ---- Phase 2: 10 CRX gates (complex from here) ----
    float r0 = v0, r1 = v1, r2 = v2, r3 = v3;
    float i0 = 0.f, i1 = 0.f, i2 = 0.f, i3 = 0.f;

#define CRX_G(gi, cmask, PART) {                                             \
    const float c = RLF(cv, 32 + (gi)), s = RLF(sv, 32 + (gi));              \
    const bool ct = (lane & (cmask)) != 0;                                   \
    float pr, pi, nr, ni;                                                    \
    pr = PART(r0); pi = PART(i0);                                            \
    nr = c*r0 + s*pi; ni = c*i0 - s*pr; r0 = ct?nr:r0; i0 = ct?ni:i0;        \
    pr = PART(r1); pi = PART(i1);                                            \
    nr = c*r1 + s*pi; ni = c*i1 - s*pr; r1 = ct?nr:r1; i1 = ct?ni:i1;        \
    pr = PART(r2); pi = PART(i2);                                            \
    nr = c*r2 + s*pi; ni = c*i2 - s*pr; r2 = ct?nr:r2; i2 = ct?ni:i2;        \
    pr = PART(r3); pi = PART(i3);                                            \
    nr = c*r3 + s*pi; ni = c*i3 - s*pr; r3 = ct?nr:r3; i3 = ct?ni:i3; }

    CRX_G(0, 32, PART16)   // ctrl lane^32, target lane^16
    CRX_G(1, 16, PX8)
    CRX_G(2,  8, PX4)
    CRX_G(3,  4, PX2)
    CRX_G(4,  2, PX1)
    {   // gate 5: ctrl lane bit0, target amp bit1 (slot pairs (0,2),(1,3))
        const float c = RLF(cv, 37), s = RLF(sv, 37);
        const float nr0 = c*r0 + s*i2, ni0 = c*i0 - s*r2;
        const float nr2 = c*r2 + s*i0, ni2 = c*i2 - s*r0;
        const float nr1 = c*r1 + s*i3, ni1 = c*i1 - s*r3;
        const float nr3 = c*r3 + s*i1, ni3 = c*i3 - s*r1;
        r0 = l0?nr0:r0; i0 = l0?ni0:i0; r1 = l0?nr1:r1; i1 = l0?ni1:i1;
        r2 = l0?nr2:r2; i2 = l0?ni2:i2; r3 = l0?nr3:r3; i3 = l0?ni3:i3;
    }
    {   // gate 6: ctrl slot bit1 (slots 2,3), target amp bit0 (pair (2,3))
        const float c = RLF(cv, 38), s = RLF(sv, 38);
        const float nr2 = c*r2 + s*i3, ni2 = c*i2 - s*r3;
        const float nr3 = c*r3 + s*i2, ni3 = c*i3 - s*r2;
        r2 = nr2; i2 = ni2; r3 = nr3; i3 = ni3;
    }
    {   // gate 7: ctrl slot bit0 (slots 1,3), target amp bit7 (lane^32)
        const float c = RLF(cv, 39), s = RLF(sv, 39);
        const float pr1 = px32(r1, lane), pi1 = px32(i1, lane);
        const float pr3 = px32(r3, lane), pi3 = px32(i3, lane);
        const float nr1 = c*r1 + s*pi1, ni1 = c*i1 - s*pr1;
        const float nr3 = c*r3 + s*pi3, ni3 = c*i3 - s*pr3;
        r1 = nr1; i1 = ni1; r3 = nr3; i3 = ni3;
    }
    CRX_G(8, 32, PART16)
    CRX_G(9, 16, PX8)

    // ---- probabilities, <Z_3> (amp bit4 -> lane bit2), <Z_7> (amp bit0 -> slot0) ----
    const float p0 = r0*r0 + i0*i0, p1 = r1*r1 + i1*i1;
    const float p2 = r2*r2 + i2*i2, p3 = r3*r3 + i3*i3;
    float vq7 = (p0 + p2) - (p1 + p3);
    float vq3 = (lane & 4) ? -(p0 + p1 + p2 + p3) : (p0 + p1 + p2 + p3);
    vq3 += PX1(vq3);          vq7 += PX1(vq7);
    vq3 += PX2(vq3);          vq7 += PX2(vq7);
    vq3 += PX4(vq3);          vq7 += PX4(vq7);
    vq3 += PX8(vq3);          vq7 += PX8(vq7);
    vq3 += px16(vq3, lane);   vq7 += px16(vq7, lane);
    vq3 += px32(vq3, lane);   vq7 += px32(vq7, lane);

    // ---- MLP (all lanes redundantly; lane 0 stores) ----
    float acc = b2[0];
    #pragma unroll
    for (int u = 0; u < 10; ++u) {
        const float z = w1[2*u] * vq3 + w1[2*u + 1] * vq7 + b1[u];
        const float e = __expf(2.0f * z);
        acc += w2[u] * (1.0f - 2.0f * __builtin_amdgcn_rcpf(e + 1.0f));
    }
    if (lane == 0) out[b] = __builtin_amdgcn_rcpf(1.0f + __expf(-acc));
}

extern "C" void kernel_launch(void* const* d_in, const int* in_sizes, int n_in,
                              void* d_out, int out_size, void* d_ws, size_t ws_size,
                              hipStream_t stream) {
    const float* x         = (const float*)d_in[0];
    const float* crx_theta = (const float*)d_in[1];
    const float* w1        = (const float*)d_in[2];
    const float* b1        = (const float*)d_in[3];
    const float* w2        = (const float*)d_in[4];
    const float* b2        = (const float*)d_in[5];
    float* out = (float*)d_out;

    const int B = in_sizes[0] / 32;  // x is (B, 4, 8)
    vqcnn_wave<<<B / 4, 256, 0, stream>>>(x, crx_theta, w1, b1, w2, b2, out);
}

// Round 4
// 83.469 us; speedup vs baseline: 1.6627x; 1.1345x over previous
//
#include <hip/hip_runtime.h>
#include <math.h>

// One wave per batch element; 256 amps = 64 lanes x 4 slots (amp = lane*4+slot).
// Round-4 changes: (1) __launch_bounds__(256,8) caps VGPR at 64 -> 8 waves/SIMD
// resident to hide cross-lane/readlane hazards; (2) cycle-0 RY layer replaced by
// closed-form product state (|0> -> prod of per-qubit (cos,sin)); (3) xor16/32
// via 1-instr precomputed-address ds_bpermute (drops the 3-instr swap-select);
// (4) MLP parallel across lanes 0..9 (one hidden unit/lane, 2 trans ops total).
// Qubit q <-> amp bit (7-q); amp bits 7..2 = lane bits 5..0, bits 1..0 = slot.

#define RLF(v, i) __int_as_float(__builtin_amdgcn_readlane(__float_as_int(v), (i)))
#define BPF(a, v) __int_as_float(__builtin_amdgcn_ds_bpermute((a), __float_as_int(v)))
#define DPPF(v, ctrl) __uint_as_float((unsigned)__builtin_amdgcn_update_dpp( \
    0, (int)__float_as_uint(v), (ctrl), 0xf, 0xf, true))
#define PX1(v)  DPPF((v), 0xB1)               // quad_perm [1,0,3,2] : lane^1
#define PX2(v)  DPPF((v), 0x4E)               // quad_perm [2,3,0,1] : lane^2
#define PX4(v)  DPPF(DPPF((v), 0x141), 0x1B)  // half_mirror(^7) o quad(^3) = ^4
#define PX8(v)  DPPF((v), 0x128)              // row_ror:8 == lane^8 within row16
#define PX16(v) BPF(a16, (v))
#define PX32(v) BPF(a32, (v))

__global__ __launch_bounds__(256, 8) void vqcnn_wave(
    const float* __restrict__ x,          // (B, 4, 8)
    const float* __restrict__ crx_theta,  // (10,)
    const float* __restrict__ w1,         // (10, 2)
    const float* __restrict__ b1,         // (10,)
    const float* __restrict__ w2,         // (1, 10)
    const float* __restrict__ b2,         // (1,)
    float* __restrict__ out)              // (B, 1)
{
    const int lane = threadIdx.x & 63;
    const int b    = blockIdx.x * 4 + (threadIdx.x >> 6);

    // per-wave angle table: lanes 0..31 RY, lanes 32..41 CRX
    float cv, sv;
    {
        float ang = 0.0f;
        if (lane < 32)      ang = x[b * 32 + lane];
        else if (lane < 42) ang = crx_theta[lane - 32];
        __sincosf(0.5f * ang, &sv, &cv);
    }

    // precomputed bpermute byte addresses
    const int a16 = (lane ^ 16) << 2;
    const int a32 = (lane ^ 32) << 2;
    const int g4  = (lane ^ (lane >> 1)) << 2;  // gray(lane)*4 : ring src lane
    const int g4b = g4 ^ (48 << 2);
    const bool l0 = (lane & 1) != 0;

    // ---- cycle 0: product state |0> -> prod_q RY(q), then ring ----
    float v0, v1, v2, v3;
    {
        float L = (lane & 32) ? RLF(sv, 0) : RLF(cv, 0);
        L *= (lane & 16) ? RLF(sv, 1) : RLF(cv, 1);
        L *= (lane &  8) ? RLF(sv, 2) : RLF(cv, 2);
        L *= (lane &  4) ? RLF(sv, 3) : RLF(cv, 3);
        L *= (lane &  2) ? RLF(sv, 4) : RLF(cv, 4);
        L *= (lane &  1) ? RLF(sv, 5) : RLF(cv, 5);
        const float c6 = RLF(cv, 6), s6 = RLF(sv, 6);
        const float c7 = RLF(cv, 7), s7 = RLF(sv, 7);
        const float Lc6 = L * c6, Ls6 = L * s6;
        v0 = Lc6 * c7; v1 = Lc6 * s7; v2 = Ls6 * c7; v3 = Ls6 * s7;
    }
#define RING() {                                                             \
    const float t0a = BPF(g4,  v0), t0b = BPF(g4,  v2);                      \
    const float t1a = BPF(g4b, v1), t1b = BPF(g4b, v3);                      \
    const float t2a = BPF(g4,  v3), t2b = BPF(g4,  v1);                      \
    const float t3a = BPF(g4b, v2), t3b = BPF(g4b, v0);                      \
    v0 = l0 ? t0b : t0a;  v1 = l0 ? t1b : t1a;                               \
    v2 = l0 ? t2b : t2a;  v3 = l0 ? t3b : t3a; }
    RING()

#define RY_G(ia, mask, PART) {                                               \
    const float c = RLF(cv, (ia)), s = RLF(sv, (ia));                        \
    const float ss = (lane & (mask)) ? s : -s;                               \
    const float p0 = PART(v0), p1 = PART(v1);                                \
    const float p2 = PART(v2), p3 = PART(v3);                                \
    v0 = fmaf(ss, p0, c * v0); v1 = fmaf(ss, p1, c * v1);                    \
    v2 = fmaf(ss, p2, c * v2); v3 = fmaf(ss, p3, c * v3); }

#define RY_SLOT1(ia) {                                                       \
    const float c = RLF(cv, (ia)), s = RLF(sv, (ia));                        \
    const float n0 = c*v0 - s*v2, n2 = s*v0 + c*v2;                          \
    const float n1 = c*v1 - s*v3, n3 = s*v1 + c*v3;                          \
    v0 = n0; v1 = n1; v2 = n2; v3 = n3; }

#define RY_SLOT0(ia) {                                                       \
    const float c = RLF(cv, (ia)), s = RLF(sv, (ia));                        \
    const float n0 = c*v0 - s*v1, n1 = s*v0 + c*v1;                          \
    const float n2 = c*v2 - s*v3, n3 = s*v2 + c*v3;                          \
    v0 = n0; v1 = n1; v2 = n2; v3 = n3; }

    // ---- cycles 1..3: 8 RY + composed CNOT ring, real arithmetic ----
    #pragma unroll
    for (int cyc = 1; cyc < 4; ++cyc) {
        const int base = cyc * 8;
        RY_G(base + 0, 32, PX32)
        RY_G(base + 1, 16, PX16)
        RY_G(base + 2,  8, PX8)
        RY_G(base + 3,  4, PX4)
        RY_G(base + 4,  2, PX2)
        RY_G(base + 5,  1, PX1)
        RY_SLOT1(base + 6)
        RY_SLOT0(base + 7)
        RING()
    }

    // ---- Phase 2: 10 CRX gates (complex from here) ----
    float r0 = v0, r1 = v1, r2 = v2, r3 = v3;
    float i0 = 0.f, i1 = 0.f, i2 = 0.f, i3 = 0.f;

#define CRX_G(gi, cmask, PART) {                                             \
    const float c = RLF(cv, 32 + (gi)), s = RLF(sv, 32 + (gi));              \
    const bool ct = (lane & (cmask)) != 0;                                   \
    float pr, pi, nr, ni;                                                    \
    pr = PART(r0); pi = PART(i0);                                            \
    nr = c*r0 + s*pi; ni = c*i0 - s*pr; r0 = ct?nr:r0; i0 = ct?ni:i0;        \
    pr = PART(r1); pi = PART(i1);                                            \
    nr = c*r1 + s*pi; ni = c*i1 - s*pr; r1 = ct?nr:r1; i1 = ct?ni:i1;        \
    pr = PART(r2); pi = PART(i2);                                            \
    nr = c*r2 + s*pi; ni = c*i2 - s*pr; r2 = ct?nr:r2; i2 = ct?ni:i2;        \
    pr = PART(r3); pi = PART(i3);                                            \
    nr = c*r3 + s*pi; ni = c*i3 - s*pr; r3 = ct?nr:r3; i3 = ct?ni:i3; }

    CRX_G(0, 32, PX16)   // ctrl lane^32, target lane^16
    CRX_G(1, 16, PX8)
    CRX_G(2,  8, PX4)
    CRX_G(3,  4, PX2)
    CRX_G(4,  2, PX1)
    {   // gate 5: ctrl lane bit0, target amp bit1 (slot pairs (0,2),(1,3))
        const float c = RLF(cv, 37), s = RLF(sv, 37);
        const float nr0 = c*r0 + s*i2, ni0 = c*i0 - s*r2;
        const float nr2 = c*r2 + s*i0, ni2 = c*i2 - s*r0;
        const float nr1 = c*r1 + s*i3, ni1 = c*i1 - s*r3;
        const float nr3 = c*r3 + s*i1, ni3 = c*i3 - s*r1;
        r0 = l0?nr0:r0; i0 = l0?ni0:i0; r1 = l0?nr1:r1; i1 = l0?ni1:i1;
        r2 = l0?nr2:r2; i2 = l0?ni2:i2; r3 = l0?nr3:r3; i3 = l0?ni3:i3;
    }
    {   // gate 6: ctrl slot bit1 (slots 2,3), target amp bit0 (pair (2,3))
        const float c = RLF(cv, 38), s = RLF(sv, 38);
        const float nr2 = c*r2 + s*i3, ni2 = c*i2 - s*r3;
        const float nr3 = c*r3 + s*i2, ni3 = c*i3 - s*r2;
        r2 = nr2; i2 = ni2; r3 = nr3; i3 = ni3;
    }
    {   // gate 7: ctrl slot bit0 (slots 1,3), target amp bit7 (lane^32)
        const float c = RLF(cv, 39), s = RLF(sv, 39);
        const float pr1 = PX32(r1), pi1 = PX32(i1);
        const float pr3 = PX32(r3), pi3 = PX32(i3);
        const float nr1 = c*r1 + s*pi1, ni1 = c*i1 - s*pr1;
        const float nr3 = c*r3 + s*pi3, ni3 = c*i3 - s*pr3;
        r1 = nr1; i1 = ni1; r3 = nr3; i3 = ni3;
    }
    CRX_G(8, 32, PX16)
    CRX_G(9, 16, PX8)

    // ---- probabilities, <Z_3> (amp bit4 -> lane bit2), <Z_7> (amp bit0 -> slot0) ----
    const float p0 = r0*r0 + i0*i0, p1 = r1*r1 + i1*i1;
    const float p2 = r2*r2 + i2*i2, p3 = r3*r3 + i3*i3;
    float vq7 = (p0 + p2) - (p1 + p3);
    float vq3 = (lane & 4) ? -(p0 + p1 + p2 + p3) : (p0 + p1 + p2 + p3);
    vq3 += PX1(vq3);   vq7 += PX1(vq7);
    vq3 += PX2(vq3);   vq7 += PX2(vq7);
    vq3 += PX4(vq3);   vq7 += PX4(vq7);
    vq3 += PX8(vq3);   vq7 += PX8(vq7);
    vq3 += PX16(vq3);  vq7 += PX16(vq7);
    vq3 += PX32(vq3);  vq7 += PX32(vq7);

    // ---- MLP: lane u (<10) computes hidden unit u; reduce over row 0..15 ----
    float wa = 0.f, wb = 0.f, bb = 0.f, wc = 0.f;
    if (lane < 10) {
        wa = w1[2 * lane];
        wb = w1[2 * lane + 1];
        bb = b1[lane];
        wc = w2[lane];
    }
    const float z = fmaf(wa, vq3, fmaf(wb, vq7, bb));
    const float e = __expf(2.0f * z);
    const float h = 1.0f - 2.0f * __builtin_amdgcn_rcpf(e + 1.0f);  // tanh(z)
    float acc = wc * h;                     // lanes >=10 contribute 0
    acc += PX1(acc);
    acc += PX2(acc);
    acc += PX4(acc);
    acc += PX8(acc);                        // sum over lanes 0..15 (row-local)
    if (lane == 0)
        out[b] = __builtin_amdgcn_rcpf(1.0f + __expf(-(acc + b2[0])));
}

extern "C" void kernel_launch(void* const* d_in, const int* in_sizes, int n_in,
                              void* d_out, int out_size, void* d_ws, size_t ws_size,
                              hipStream_t stream) {
    const float* x         = (const float*)d_in[0];
    const float* crx_theta = (const float*)d_in[1];
    const float* w1        = (const float*)d_in[2];
    const float* b1        = (const float*)d_in[3];
    const float* w2        = (const float*)d_in[4];
    const float* b2        = (const float*)d_in[5];
    float* out = (float*)d_out;

    const int B = in_sizes[0] / 32;  // x is (B, 4, 8)
    vqcnn_wave<<<B / 4, 256, 0, stream>>>(x, crx_theta, w1, b1, w2, b2, out);
}

// Round 5
// 81.483 us; speedup vs baseline: 1.7032x; 1.0244x over previous
//
#include <hip/hip_runtime.h>
#include <math.h>

// Two states per wave; 256 amps/state = 64 lanes x 4 slots (amp = lane*4+slot).
// State A in .x, state B in .y of float2 registers -> all butterfly math lowers
// to packed v_pk_{mul,fma}_f32 (full-rate on gfx950), halving VALU instrs per
// state and doubling per-wave ILP to hide cross-lane latencies. 8192 waves
// total = exactly 8 waves/SIMD, all resident (launch_bounds(256,8)).
// Phase 1 real-only; composed-CNOT ring via gray-code ds_bpermute gather;
// xor1/2/4/8 exchanges on the VALU pipe via DPP; xor16/32 via ds_bpermute.
// Qubit q <-> amp bit (7-q); amp bits 7..2 = lane bits 5..0, bits 1..0 = slot.

typedef float f2 __attribute__((ext_vector_type(2)));

#define RLF(v, i) __int_as_float(__builtin_amdgcn_readlane(__float_as_int(v), (i)))
#define BPF(a, v) __int_as_float(__builtin_amdgcn_ds_bpermute((a), __float_as_int(v)))
#define DPPF(v, ctrl) __uint_as_float((unsigned)__builtin_amdgcn_update_dpp( \
    0, (int)__float_as_uint(v), (ctrl), 0xf, 0xf, true))

__device__ __forceinline__ f2 mk2(float a, float b) { f2 r; r.x = a; r.y = b; return r; }

#define PX1S(v)  DPPF((v), 0xB1)
#define PX2S(v)  DPPF((v), 0x4E)
#define PX4S(v)  DPPF(DPPF((v), 0x141), 0x1B)
#define PX8S(v)  DPPF((v), 0x128)

#define PX1(v)  mk2(PX1S((v).x), PX1S((v).y))
#define PX2(v)  mk2(PX2S((v).x), PX2S((v).y))
#define PX4(v)  mk2(PX4S((v).x), PX4S((v).y))
#define PX8(v)  mk2(PX8S((v).x), PX8S((v).y))
#define PX16(v) mk2(BPF(a16, (v).x), BPF(a16, (v).y))
#define PX32(v) mk2(BPF(a32, (v).x), BPF(a32, (v).y))
#define FMA2(a, b, c) __builtin_elementwise_fma((a), (b), (c))

__global__ __launch_bounds__(256, 8) void vqcnn_wave(
    const float* __restrict__ x,          // (B, 4, 8)
    const float* __restrict__ crx_theta,  // (10,)
    const float* __restrict__ w1,         // (10, 2)
    const float* __restrict__ b1,         // (10,)
    const float* __restrict__ w2,         // (1, 10)
    const float* __restrict__ b2,         // (1,)
    float* __restrict__ out)              // (B, 1)
{
    const int lane = threadIdx.x & 63;
    const int bA   = blockIdx.x * 8 + (threadIdx.x >> 6) * 2;
    const int bB   = bA + 1;

    // per-wave angle tables: lanes 0..31 RY (per state), lanes 32..41 CRX (shared)
    float cvA, svA, cvB, svB;
    {
        float angA = 0.0f, angB = 0.0f;
        if (lane < 32) {
            angA = x[bA * 32 + lane];
            angB = x[bB * 32 + lane];
        } else if (lane < 42) {
            angA = angB = crx_theta[lane - 32];
        }
        __sincosf(0.5f * angA, &svA, &cvA);
        __sincosf(0.5f * angB, &svB, &cvB);
    }

    // bpermute byte addresses
    const int a16 = (lane ^ 16) << 2;
    const int a32 = (lane ^ 32) << 2;
    const int g4  = (lane ^ (lane >> 1)) << 2;  // gray(lane)*4 : ring src lane
    const int g4b = g4 ^ (48 << 2);
    const bool l0 = (lane & 1) != 0;

#define RL2C(i) mk2(RLF(cvA, (i)), RLF(cvB, (i)))
#define RL2S(i) mk2(RLF(svA, (i)), RLF(svB, (i)))

    // ---- cycle 0: product state |0> -> prod_q RY(q) ----
    f2 vv0, vv1, vv2, vv3;
    {
#define SEL0(bit, i) ((lane & (bit)) ? RL2S(i) : RL2C(i))
        f2 L = SEL0(32, 0) * SEL0(16, 1);
        L = L * SEL0(8, 2);
        L = L * SEL0(4, 3);
        L = L * SEL0(2, 4);
        L = L * SEL0(1, 5);
        const f2 c6 = RL2C(6), s6 = RL2S(6);
        const f2 c7 = RL2C(7), s7 = RL2S(7);
        const f2 Lc6 = L * c6, Ls6 = L * s6;
        vv0 = Lc6 * c7; vv1 = Lc6 * s7; vv2 = Ls6 * c7; vv3 = Ls6 * s7;
    }

#define RING() {                                                             \
    const f2 t0a = PXG(vv0), t0b = PXG(vv2);                                 \
    const f2 t1a = PXGB(vv1), t1b = PXGB(vv3);                               \
    const f2 t2a = PXG(vv3), t2b = PXG(vv1);                                 \
    const f2 t3a = PXGB(vv2), t3b = PXGB(vv0);                               \
    vv0 = l0 ? t0b : t0a;  vv1 = l0 ? t1b : t1a;                             \
    vv2 = l0 ? t2b : t2a;  vv3 = l0 ? t3b : t3a; }
#define PXG(v)  mk2(BPF(g4,  (v).x), BPF(g4,  (v).y))
#define PXGB(v) mk2(BPF(g4b, (v).x), BPF(g4b, (v).y))
    RING()

#define RY_G(ia, mask, PART) {                                               \
    const f2 c = RL2C(ia), s = RL2S(ia);                                     \
    const f2 ss = (lane & (mask)) ? s : -s;                                  \
    const f2 p0 = PART(vv0), p1 = PART(vv1);                                 \
    const f2 p2 = PART(vv2), p3 = PART(vv3);                                 \
    vv0 = FMA2(ss, p0, c * vv0); vv1 = FMA2(ss, p1, c * vv1);                \
    vv2 = FMA2(ss, p2, c * vv2); vv3 = FMA2(ss, p3, c * vv3); }

#define RY_SLOT1(ia) {                                                       \
    const f2 c = RL2C(ia), s = RL2S(ia);                                     \
    const f2 n0 = c*vv0 - s*vv2, n2 = FMA2(s, vv0, c*vv2);                   \
    const f2 n1 = c*vv1 - s*vv3, n3 = FMA2(s, vv1, c*vv3);                   \
    vv0 = n0; vv1 = n1; vv2 = n2; vv3 = n3; }

#define RY_SLOT0(ia) {                                                       \
    const f2 c = RL2C(ia), s = RL2S(ia);                                     \
    const f2 n0 = c*vv0 - s*vv1, n1 = FMA2(s, vv0, c*vv1);                   \
    const f2 n2 = c*vv2 - s*vv3, n3 = FMA2(s, vv2, c*vv3);                   \
    vv0 = n0; vv1 = n1; vv2 = n2; vv3 = n3; }

    // ---- cycles 1..3: 8 RY + composed CNOT ring, real arithmetic ----
    #pragma unroll
    for (int cyc = 1; cyc < 4; ++cyc) {
        const int base = cyc * 8;
        RY_G(base + 0, 32, PX32)
        RY_G(base + 1, 16, PX16)
        RY_G(base + 2,  8, PX8)
        RY_G(base + 3,  4, PX4)
        RY_G(base + 4,  2, PX2)
        RY_G(base + 5,  1, PX1)
        RY_SLOT1(base + 6)
        RY_SLOT0(base + 7)
        RING()
    }

    // ---- Phase 2: 10 CRX gates (complex from here) ----
    f2 rr0 = vv0, rr1 = vv1, rr2 = vv2, rr3 = vv3;
    f2 ii0 = {0.f, 0.f}, ii1 = {0.f, 0.f}, ii2 = {0.f, 0.f}, ii3 = {0.f, 0.f};

#define CRX_G(gi, cmask, PART) {                                             \
    const f2 c = RL2C(32 + (gi)), s = RL2S(32 + (gi));                       \
    const bool ct = (lane & (cmask)) != 0;                                   \
    f2 pr, pi, nr, ni;                                                       \
    pr = PART(rr0); pi = PART(ii0);                                          \
    nr = FMA2(s, pi, c*rr0); ni = c*ii0 - s*pr;                              \
    rr0 = ct?nr:rr0; ii0 = ct?ni:ii0;                                        \
    pr = PART(rr1); pi = PART(ii1);                                          \
    nr = FMA2(s, pi, c*rr1); ni = c*ii1 - s*pr;                              \
    rr1 = ct?nr:rr1; ii1 = ct?ni:ii1;                                        \
    pr = PART(rr2); pi = PART(ii2);                                          \
    nr = FMA2(s, pi, c*rr2); ni = c*ii2 - s*pr;                              \
    rr2 = ct?nr:rr2; ii2 = ct?ni:ii2;                                        \
    pr = PART(rr3); pi = PART(ii3);                                          \
    nr = FMA2(s, pi, c*rr3); ni = c*ii3 - s*pr;                              \
    rr3 = ct?nr:rr3; ii3 = ct?ni:ii3; }

    CRX_G(0, 32, PX16)   // ctrl lane^32, target lane^16
    CRX_G(1, 16, PX8)
    CRX_G(2,  8, PX4)
    CRX_G(3,  4, PX2)
    CRX_G(4,  2, PX1)
    {   // gate 5: ctrl lane bit0, target amp bit1 (slot pairs (0,2),(1,3))
        const f2 c = RL2C(37), s = RL2S(37);
        const f2 nr0 = FMA2(s, ii2, c*rr0), ni0 = c*ii0 - s*rr2;
        const f2 nr2 = FMA2(s, ii0, c*rr2), ni2 = c*ii2 - s*rr0;
        const f2 nr1 = FMA2(s, ii3, c*rr1), ni1 = c*ii1 - s*rr3;
        const f2 nr3 = FMA2(s, ii1, c*rr3), ni3 = c*ii3 - s*rr1;
        rr0 = l0?nr0:rr0; ii0 = l0?ni0:ii0; rr1 = l0?nr1:rr1; ii1 = l0?ni1:ii1;
        rr2 = l0?nr2:rr2; ii2 = l0?ni2:ii2; rr3 = l0?nr3:rr3; ii3 = l0?ni3:ii3;
    }
    {   // gate 6: ctrl slot bit1 (slots 2,3), target amp bit0 (pair (2,3))
        const f2 c = RL2C(38), s = RL2S(38);
        const f2 nr2 = FMA2(s, ii3, c*rr2), ni2 = c*ii2 - s*rr3;
        const f2 nr3 = FMA2(s, ii2, c*rr3), ni3 = c*ii3 - s*rr2;
        rr2 = nr2; ii2 = ni2; rr3 = nr3; ii3 = ni3;
    }
    {   // gate 7: ctrl slot bit0 (slots 1,3), target amp bit7 (lane^32)
        const f2 c = RL2C(39), s = RL2S(39);
        const f2 pr1 = PX32(rr1), pi1 = PX32(ii1);
        const f2 pr3 = PX32(rr3), pi3 = PX32(ii3);
        const f2 nr1 = FMA2(s, pi1, c*rr1), ni1 = c*ii1 - s*pr1;
        const f2 nr3 = FMA2(s, pi3, c*rr3), ni3 = c*ii3 - s*pr3;
        rr1 = nr1; ii1 = ni1; rr3 = nr3; ii3 = ni3;
    }
    CRX_G(8, 32, PX16)
    CRX_G(9, 16, PX8)

    // ---- probabilities, <Z_3> (amp bit4 -> lane bit2), <Z_7> (amp bit0 -> slot0) ----
    const f2 p0 = FMA2(rr0, rr0, ii0*ii0), p1 = FMA2(rr1, rr1, ii1*ii1);
    const f2 p2 = FMA2(rr2, rr2, ii2*ii2), p3 = FMA2(rr3, rr3, ii3*ii3);
    const f2 sum = (p0 + p1) + (p2 + p3);
    f2 vq7 = (p0 + p2) - (p1 + p3);
    f2 vq3 = (lane & 4) ? -sum : sum;
    vq3 = vq3 + PX1(vq3);   vq7 = vq7 + PX1(vq7);
    vq3 = vq3 + PX2(vq3);   vq7 = vq7 + PX2(vq7);
    vq3 = vq3 + PX4(vq3);   vq7 = vq7 + PX4(vq7);
    vq3 = vq3 + PX8(vq3);   vq7 = vq7 + PX8(vq7);
    vq3 = vq3 + PX16(vq3);  vq7 = vq7 + PX16(vq7);
    vq3 = vq3 + PX32(vq3);  vq7 = vq7 + PX32(vq7);

    // ---- MLP: lane u (<10) computes hidden unit u for both states ----
    float wa = 0.f, wb = 0.f, bb = 0.f, wc = 0.f;
    if (lane < 10) {
        wa = w1[2 * lane];
        wb = w1[2 * lane + 1];
        bb = b1[lane];
        wc = w2[lane];
    }
    const f2 z = FMA2(mk2(wa, wa), vq3, FMA2(mk2(wb, wb), vq7, mk2(bb, bb)));
    const f2 e = mk2(__expf(2.0f * z.x), __expf(2.0f * z.y));
    const f2 h = mk2(1.0f - 2.0f * __builtin_amdgcn_rcpf(e.x + 1.0f),
                     1.0f - 2.0f * __builtin_amdgcn_rcpf(e.y + 1.0f));  // tanh
    f2 acc = mk2(wc, wc) * h;               // lanes >=10 contribute 0
    acc = acc + PX1(acc);
    acc = acc + PX2(acc);
    acc = acc + PX4(acc);
    acc = acc + PX8(acc);                   // sum over lanes 0..15 (row-local)
    if (lane == 0) {
        const float bias = b2[0];
        out[bA] = __builtin_amdgcn_rcpf(1.0f + __expf(-(acc.x + bias)));
        out[bB] = __builtin_amdgcn_rcpf(1.0f + __expf(-(acc.y + bias)));
    }
}

extern "C" void kernel_launch(void* const* d_in, const int* in_sizes, int n_in,
                              void* d_out, int out_size, void* d_ws, size_t ws_size,
                              hipStream_t stream) {
    const float* x         = (const float*)d_in[0];
    const float* crx_theta = (const float*)d_in[1];
    const float* w1        = (const float*)d_in[2];
    const float* b1        = (const float*)d_in[3];
    const float* w2        = (const float*)d_in[4];
    const float* b2        = (const float*)d_in[5];
    float* out = (float*)d_out;

    const int B = in_sizes[0] / 32;  // x is (B, 4, 8)
    vqcnn_wave<<<B / 8, 256, 0, stream>>>(x, crx_theta, w1, b1, w2, b2, out);
}